// Round 5
// baseline (296.254 us; speedup 1.0000x reference)
//
#include <hip/hip_runtime.h>

typedef unsigned short u16;
typedef short s16x8 __attribute__((ext_vector_type(8)));
typedef float f32x4 __attribute__((ext_vector_type(4)));

#define B_   8
#define N_   24000
#define M_   6000
#define K_   32
#define CIN  64
#define CMID 128
#define COUT 256
#define KP1  96   // 67 zero-padded to 3x32 for MFMA K-steps

// Static device globals — no ws_size assumption, graph-capture safe,
// fully rewritten on every call.
__device__ __align__(16) u16 g_W1p[CMID * KP1];                 // 24.6 KB bf16
__device__ __align__(16) u16 g_W2b[COUT * CMID];                // 65.5 KB bf16
__device__ __align__(16) u16 g_Yf[(size_t)B_ * N_ * COUT];      // 98.3 MB bf16

__device__ __forceinline__ float bf2f(u16 u) {
    return __uint_as_float(((unsigned)u) << 16);
}
__device__ __forceinline__ u16 f2bf(float f) {  // fp32 -> bf16 RNE
    unsigned u = __float_as_uint(f);
    u += 0x7FFFu + ((u >> 16) & 1u);
    return (u16)(u >> 16);
}

// ---------------------------------------------------------------------------
// Kernel 0: convert fp32 weights to bf16.
//   t < 12288          : g_W1p[128][96] = pad(W1[128][67])
//   t in [12288,45056) : g_W2b[256*128] = W2
// ---------------------------------------------------------------------------
__global__ void prep_weights(const float* __restrict__ W1,
                             const float* __restrict__ W2) {
    int t = blockIdx.x * 256 + threadIdx.x;   // 0..45055
    if (t < CMID * KP1) {
        int m = t / KP1, k = t % KP1;
        g_W1p[t] = (k < 67) ? f2bf(W1[m * 67 + k]) : (u16)0;
    } else {
        int i = t - CMID * KP1;               // 0..32767
        g_W2b[i] = f2bf(W2[i]);
    }
}

// ---------------------------------------------------------------------------
// Kernel 1: fused conv1+relu+conv2+relu over support points.
// Block = 64 points of one batch, 256 threads (4 waves).
// GEMM1: H[128][64] = relu(W1p[128][96] @ X[96][64] + b1)   (bf16 MFMA)
// GEMM2: Y[256][64] = relu(W2 [256][128] @ H[128][64] + b2)
// fp32 inputs are packed to bf16 at staging; biases added in fp32.
// Output to g_Yf as [B][N][256] bf16 (point-major rows for the gather).
// ---------------------------------------------------------------------------
__global__ __launch_bounds__(256) void conv_fused(
        const float* __restrict__ feat, const float* __restrict__ xyz,
        const float* __restrict__ b1,  const float* __restrict__ b2) {
    // LDS (u16): Xs [64][104] at 0, Hs [64][136] at 6656,
    // Ys [64][264] aliases the whole buffer after GEMM2.
    __shared__ __align__(16) u16 sm[16896];
    u16* Xs = sm;
    u16* Hs = sm + 6656;
    u16* Ys = sm;

    const int tid  = threadIdx.x;
    const int b    = blockIdx.y;
    const int n0   = blockIdx.x * 64;
    const int w    = tid >> 6;      // wave id 0..3
    const int L    = tid & 63;      // lane
    const int ln   = L & 15;
    const int quad = L >> 4;

    // ---- stage X tile: Xs[p][k] = concat(features[:,p], xyz[p,:]), k 67..95=0
    if (tid < 64) {
        uint4 z; z.x = z.y = z.z = z.w = 0u;
        u16* xr = Xs + tid * 104;
        *(uint4*)(xr + 64) = z; *(uint4*)(xr + 72) = z;
        *(uint4*)(xr + 80) = z; *(uint4*)(xr + 88) = z;
        const float* s = xyz + (size_t)(b * N_ + n0 + tid) * 3;
        xr[64] = f2bf(s[0]); xr[65] = f2bf(s[1]); xr[66] = f2bf(s[2]);
    }
#pragma unroll
    for (int it = 0; it < 4; ++it) {
        int idx = it * 256 + tid;          // 0..1023
        int c   = idx >> 4;                // 0..63
        int p0  = (idx & 15) << 2;         // 0,4,..,60
        float4 v = *(const float4*)(feat + (size_t)(b * CIN + c) * N_ + n0 + p0);
        u16* dst = Xs + p0 * 104 + c;
        dst[0]   = f2bf(v.x);
        dst[104] = f2bf(v.y);
        dst[208] = f2bf(v.z);
        dst[312] = f2bf(v.w);
    }
    __syncthreads();

    // ---- GEMM1: wave w owns m rows [w*32, w*32+32), all 64 n
    f32x4 acc1[2][4];
#pragma unroll
    for (int mt = 0; mt < 2; ++mt)
#pragma unroll
        for (int nt = 0; nt < 4; ++nt) {
            f32x4 zz = {0.f, 0.f, 0.f, 0.f};
            acc1[mt][nt] = zz;
        }
#pragma unroll
    for (int k0 = 0; k0 < KP1; k0 += 32) {
        s16x8 af[2], bf[4];
#pragma unroll
        for (int mt = 0; mt < 2; ++mt)
            af[mt] = *(const s16x8*)(g_W1p + (size_t)(w * 32 + mt * 16 + ln) * KP1 + k0 + quad * 8);
#pragma unroll
        for (int nt = 0; nt < 4; ++nt)
            bf[nt] = *(const s16x8*)(Xs + (nt * 16 + ln) * 104 + k0 + quad * 8);
#pragma unroll
        for (int mt = 0; mt < 2; ++mt)
#pragma unroll
            for (int nt = 0; nt < 4; ++nt)
                acc1[mt][nt] = __builtin_amdgcn_mfma_f32_16x16x32_bf16(
                    af[mt], bf[nt], acc1[mt][nt], 0, 0, 0);
    }
    // epilogue 1: bias+relu (fp32), pack bf16, Hs[p][m] (B-layout for GEMM2)
#pragma unroll
    for (int mt = 0; mt < 2; ++mt) {
        int m0 = w * 32 + mt * 16 + quad * 4;
        float4 bv = *(const float4*)(b1 + m0);
#pragma unroll
        for (int nt = 0; nt < 4; ++nt) {
            int p = nt * 16 + ln;
            float x0 = acc1[mt][nt][0] + bv.x;
            float x1 = acc1[mt][nt][1] + bv.y;
            float x2 = acc1[mt][nt][2] + bv.z;
            float x3 = acc1[mt][nt][3] + bv.w;
            ushort4 hv;
            hv.x = f2bf(x0 > 0.f ? x0 : 0.f);   // ternary: -0.0 -> +0
            hv.y = f2bf(x1 > 0.f ? x1 : 0.f);
            hv.z = f2bf(x2 > 0.f ? x2 : 0.f);
            hv.w = f2bf(x3 > 0.f ? x3 : 0.f);
            *(ushort4*)(Hs + p * 136 + m0) = hv;
        }
    }
    __syncthreads();

    // ---- GEMM2: wave w owns c rows [w*64, w*64+64)
    f32x4 acc2[4][4];
#pragma unroll
    for (int mt = 0; mt < 4; ++mt)
#pragma unroll
        for (int nt = 0; nt < 4; ++nt) {
            f32x4 zz = {0.f, 0.f, 0.f, 0.f};
            acc2[mt][nt] = zz;
        }
#pragma unroll
    for (int k0 = 0; k0 < CMID; k0 += 32) {
        s16x8 af[4], bf[4];
#pragma unroll
        for (int mt = 0; mt < 4; ++mt)
            af[mt] = *(const s16x8*)(g_W2b + (size_t)(w * 64 + mt * 16 + ln) * CMID + k0 + quad * 8);
#pragma unroll
        for (int nt = 0; nt < 4; ++nt)
            bf[nt] = *(const s16x8*)(Hs + (nt * 16 + ln) * 136 + k0 + quad * 8);
#pragma unroll
        for (int mt = 0; mt < 4; ++mt)
#pragma unroll
            for (int nt = 0; nt < 4; ++nt)
                acc2[mt][nt] = __builtin_amdgcn_mfma_f32_16x16x32_bf16(
                    af[mt], bf[nt], acc2[mt][nt], 0, 0, 0);
    }
    __syncthreads();  // Hs/Xs dead; Ys aliases them

    // epilogue 2: bias+relu, stage Ys[p][c]
#pragma unroll
    for (int mt = 0; mt < 4; ++mt) {
        int c0 = w * 64 + mt * 16 + quad * 4;
        float4 bv = *(const float4*)(b2 + c0);
#pragma unroll
        for (int nt = 0; nt < 4; ++nt) {
            int p = nt * 16 + ln;
            float x0 = acc2[mt][nt][0] + bv.x;
            float x1 = acc2[mt][nt][1] + bv.y;
            float x2 = acc2[mt][nt][2] + bv.z;
            float x3 = acc2[mt][nt][3] + bv.w;
            ushort4 yv;
            yv.x = f2bf(x0 > 0.f ? x0 : 0.f);
            yv.y = f2bf(x1 > 0.f ? x1 : 0.f);
            yv.z = f2bf(x2 > 0.f ? x2 : 0.f);
            yv.w = f2bf(x3 > 0.f ? x3 : 0.f);
            *(ushort4*)(Ys + p * 264 + c0) = yv;
        }
    }
    __syncthreads();

    // coalesced store: g_Yf[b][n0+p][0..255], 512B per point row
    u16* dstY = g_Yf + ((size_t)b * N_ + n0) * COUT;
#pragma unroll
    for (int i = 0; i < 8; ++i) {
        int g = i * 256 + tid;
        int p = g >> 5, c16 = g & 31;
        *(uint4*)(dstY + (size_t)p * COUT + c16 * 8) =
            *(const uint4*)(Ys + p * 264 + c16 * 8);
    }
}

// ---------------------------------------------------------------------------
// Kernel 2: gather neighbors + max over K. Block = 64 queries of one batch.
// One wave per query per iteration; lane holds 4 channels (8B) -> each (m,k)
// read is one coalesced 512B row. Max in raw ushort domain: post-ReLU bf16
// (sign bit always 0) is order-isomorphic to uint16 -> exact bf16 max.
// Final store converts bf16 -> fp32 (output buffer is float32).
// ---------------------------------------------------------------------------
__global__ __launch_bounds__(256) void gather_max(
        const int* __restrict__ nbr, float* __restrict__ out) {
    __shared__ __align__(16) int sidx[64 * K_];
    __shared__ __align__(16) u16 ymax[COUT * 68];  // stride 68: 8B-aligned rows

    const int tid = threadIdx.x;
    const int b   = blockIdx.y;
    const int m0  = blockIdx.x * 64;

    // stage neighbor indices (guarded for the M tail)
#pragma unroll
    for (int it = 0; it < 2; ++it) {
        int g = it * 256 + tid;            // int4 index; 4 ints stay within one m
        if (m0 + (g >> 3) < M_)
            *(int4*)(sidx + g * 4) =
                *(const int4*)(nbr + (size_t)(b * M_ + m0) * K_ + g * 4);
    }
    __syncthreads();

    const int w = tid >> 6, L = tid & 63;
    const u16* base = g_Yf + (size_t)b * N_ * COUT + L * 4;
    for (int i = 0; i < 16; ++i) {
        int ml = w * 16 + i;
        if (m0 + ml >= M_) break;
        ushort4 mx; mx.x = 0; mx.y = 0; mx.z = 0; mx.w = 0;
#pragma unroll
        for (int k = 0; k < K_; ++k) {
            int idx = __builtin_amdgcn_readfirstlane(sidx[ml * K_ + k]);
            idx = ((unsigned)idx < (unsigned)N_) ? idx : 0;   // defensive clamp
            ushort4 v = *(const ushort4*)(base + (size_t)idx * COUT);
            mx.x = v.x > mx.x ? v.x : mx.x;
            mx.y = v.y > mx.y ? v.y : mx.y;
            mx.z = v.z > mx.z ? v.z : mx.z;
            mx.w = v.w > mx.w ? v.w : mx.w;
        }
        u16* yp = ymax + (L * 4) * 68 + ml;
        yp[0] = mx.x; yp[68] = mx.y; yp[136] = mx.z; yp[204] = mx.w;
    }
    __syncthreads();

    // transpose out of LDS, expand bf16 -> fp32:
    // out[b][c][m0..m0+63], 2x float4 per thread, coalesced
    int valid = M_ - m0; if (valid > 64) valid = 64;
#pragma unroll
    for (int i = 0; i < 8; ++i) {
        int c  = i * 32 + (tid >> 3);
        int mc = (tid & 7) << 3;
        if (mc + 8 <= valid) {
            const u16* src = ymax + c * 68 + mc;
            float4 v0, v1;
            v0.x = bf2f(src[0]); v0.y = bf2f(src[1]);
            v0.z = bf2f(src[2]); v0.w = bf2f(src[3]);
            v1.x = bf2f(src[4]); v1.y = bf2f(src[5]);
            v1.z = bf2f(src[6]); v1.w = bf2f(src[7]);
            float* dst = out + (size_t)(b * COUT + c) * M_ + m0 + mc;
            *(float4*)dst       = v0;
            *(float4*)(dst + 4) = v1;
        }
    }
}

extern "C" void kernel_launch(void* const* d_in, const int* in_sizes, int n_in,
                              void* d_out, int out_size, void* d_ws, size_t ws_size,
                              hipStream_t stream) {
    // inputs (all fp32 except neighbor_idx int32), per the reference:
    // 0=query_xyz(unused) 1=support_xyz 2=features 3=neighbor_idx
    // 4=W1 5=b1 6=W2 7=b2. Output: fp32 [B][C_OUT][M].
    const float* xyz  = (const float*)d_in[1];
    const float* feat = (const float*)d_in[2];
    const int*   nbr  = (const int*)d_in[3];
    const float* W1   = (const float*)d_in[4];
    const float* b1   = (const float*)d_in[5];
    const float* W2   = (const float*)d_in[6];
    const float* b2   = (const float*)d_in[7];
    float* out = (float*)d_out;
    (void)d_ws; (void)ws_size;

    prep_weights<<<176, 256, 0, stream>>>(W1, W2);   // 176*256 = 45056
    conv_fused<<<dim3(N_ / 64, B_), 256, 0, stream>>>(feat, xyz, b1, b2);
    gather_max<<<dim3((M_ + 63) / 64, B_), 256, 0, stream>>>(nbr, out);
}

// Round 6
// 282.756 us; speedup vs baseline: 1.0477x; 1.0477x over previous
//
#include <hip/hip_runtime.h>

typedef unsigned short u16;
typedef short s16x8 __attribute__((ext_vector_type(8)));
typedef float f32x4 __attribute__((ext_vector_type(4)));

#define B_   8
#define N_   24000
#define M_   6000
#define K_   32
#define CIN  64
#define CMID 128
#define COUT 256
#define KP1  96   // 67 zero-padded to 3x32 for MFMA K-steps

// Static device globals — no ws_size assumption, graph-capture safe,
// fully rewritten on every call.
// Weights stored in MFMA *fragment order*: for each (wave w, k-step, m-tile)
// a contiguous 1 KB block where lane L holds its 16 B at offset L*8 u16.
// This turns every A-fragment load into one coalesced global_load_dwordx4
// (the R5 layout was a 16-row scatter: ~16-32 cache lines per wave-load).
__device__ __align__(16) u16 g_W1f[CMID * KP1];                 // 24.6 KB bf16
__device__ __align__(16) u16 g_W2f[COUT * CMID];                // 65.5 KB bf16
__device__ __align__(16) u16 g_Yf[(size_t)B_ * N_ * COUT];      // 98.3 MB bf16

__device__ __forceinline__ float bf2f(u16 u) {
    return __uint_as_float(((unsigned)u) << 16);
}
__device__ __forceinline__ u16 f2bf(float f) {  // fp32 -> bf16 RNE
    unsigned u = __float_as_uint(f);
    u += 0x7FFFu + ((u >> 16) & 1u);
    return (u16)(u >> 16);
}

// ---------------------------------------------------------------------------
// Kernel 0: convert fp32 weights to bf16 in fragment order.
// W1f block id = (w*3 + k0i)*2 + mt   (w<4, k0i<3, mt<2), 512 u16 each
// W2f block id = (w*4 + k0i)*4 + mt   (w<4, k0i<4, mt<4), 512 u16 each
// element (L=quad*16+ln, j) <- W[row = wbase + mt*16 + ln][col = k0i*32+quad*8+j]
// ---------------------------------------------------------------------------
__global__ void prep_weights(const float* __restrict__ W1,
                             const float* __restrict__ W2) {
    int t = blockIdx.x * 256 + threadIdx.x;   // 0..45055
    if (t < CMID * KP1) {                     // 12288 -> W1f
        int blk = t >> 9, off = t & 511;
        int L = off >> 3, j = off & 7;
        int ln = L & 15, quad = L >> 4;
        int w = blk / 6, r = blk % 6;
        int k0i = r >> 1, mt = r & 1;
        int row = w * 32 + mt * 16 + ln;
        int col = k0i * 32 + quad * 8 + j;
        g_W1f[t] = (col < 67) ? f2bf(W1[row * 67 + col]) : (u16)0;
    } else {                                  // 32768 -> W2f
        int i = t - CMID * KP1;
        int blk = i >> 9, off = i & 511;
        int L = off >> 3, j = off & 7;
        int ln = L & 15, quad = L >> 4;
        int w = blk >> 4, r = blk & 15;
        int k0i = r >> 2, mt = r & 3;
        int row = w * 64 + mt * 16 + ln;
        int col = k0i * 32 + quad * 8 + j;
        g_W2f[i] = f2bf(W2[row * 128 + col]);
    }
}

// ---------------------------------------------------------------------------
// Kernel 1: fused conv1+relu+conv2+relu over support points.
// Block = 64 points of one batch, 256 threads (4 waves).
// GEMM1: H[128][64] = relu(W1[128][96] @ X[96][64] + b1)   (bf16 MFMA)
// GEMM2: Y[256][64] = relu(W2[256][128] @ H[128][64] + b2)
// A-fragments come from the fragment-ordered weight arrays (coalesced 1 KB
// wave-loads). Output to g_Yf as [B][N][256] bf16 (rows for the gather).
// ---------------------------------------------------------------------------
__global__ __launch_bounds__(256) void conv_fused(
        const float* __restrict__ feat, const float* __restrict__ xyz,
        const float* __restrict__ b1,  const float* __restrict__ b2) {
    // LDS (u16): Xs [64][104] at 0, Hs [64][136] at 6656,
    // Ys [64][264] aliases the whole buffer after GEMM2.
    __shared__ __align__(16) u16 sm[16896];
    u16* Xs = sm;
    u16* Hs = sm + 6656;
    u16* Ys = sm;

    const int tid  = threadIdx.x;
    const int b    = blockIdx.y;
    const int n0   = blockIdx.x * 64;
    const int w    = tid >> 6;      // wave id 0..3
    const int L    = tid & 63;      // lane
    const int ln   = L & 15;
    const int quad = L >> 4;

    // ---- stage X tile: Xs[p][k] = concat(features[:,p], xyz[p,:]), k 67..95=0
    if (tid < 64) {
        uint4 z; z.x = z.y = z.z = z.w = 0u;
        u16* xr = Xs + tid * 104;
        *(uint4*)(xr + 64) = z; *(uint4*)(xr + 72) = z;
        *(uint4*)(xr + 80) = z; *(uint4*)(xr + 88) = z;
        const float* s = xyz + (size_t)(b * N_ + n0 + tid) * 3;
        xr[64] = f2bf(s[0]); xr[65] = f2bf(s[1]); xr[66] = f2bf(s[2]);
    }
#pragma unroll
    for (int it = 0; it < 4; ++it) {
        int idx = it * 256 + tid;          // 0..1023
        int c   = idx >> 4;                // 0..63
        int p0  = (idx & 15) << 2;         // 0,4,..,60
        float4 v = *(const float4*)(feat + (size_t)(b * CIN + c) * N_ + n0 + p0);
        u16* dst = Xs + p0 * 104 + c;
        dst[0]   = f2bf(v.x);
        dst[104] = f2bf(v.y);
        dst[208] = f2bf(v.z);
        dst[312] = f2bf(v.w);
    }
    __syncthreads();

    // ---- GEMM1: wave w owns m rows [w*32, w*32+32), all 64 n
    f32x4 acc1[2][4];
#pragma unroll
    for (int mt = 0; mt < 2; ++mt)
#pragma unroll
        for (int nt = 0; nt < 4; ++nt) {
            f32x4 zz = {0.f, 0.f, 0.f, 0.f};
            acc1[mt][nt] = zz;
        }
#pragma unroll
    for (int k0i = 0; k0i < 3; ++k0i) {
        s16x8 af[2], xf[4];
#pragma unroll
        for (int mt = 0; mt < 2; ++mt)
            af[mt] = *(const s16x8*)(g_W1f + (((w * 3 + k0i) * 2 + mt) << 9) + L * 8);
#pragma unroll
        for (int nt = 0; nt < 4; ++nt)
            xf[nt] = *(const s16x8*)(Xs + (nt * 16 + ln) * 104 + k0i * 32 + quad * 8);
#pragma unroll
        for (int mt = 0; mt < 2; ++mt)
#pragma unroll
            for (int nt = 0; nt < 4; ++nt)
                acc1[mt][nt] = __builtin_amdgcn_mfma_f32_16x16x32_bf16(
                    af[mt], xf[nt], acc1[mt][nt], 0, 0, 0);
    }
    // epilogue 1: bias+relu (fp32), pack bf16, Hs[p][m] (B-layout for GEMM2)
#pragma unroll
    for (int mt = 0; mt < 2; ++mt) {
        int m0 = w * 32 + mt * 16 + quad * 4;
        float4 bv = *(const float4*)(b1 + m0);
#pragma unroll
        for (int nt = 0; nt < 4; ++nt) {
            int p = nt * 16 + ln;
            float x0 = acc1[mt][nt][0] + bv.x;
            float x1 = acc1[mt][nt][1] + bv.y;
            float x2 = acc1[mt][nt][2] + bv.z;
            float x3 = acc1[mt][nt][3] + bv.w;
            ushort4 hv;
            hv.x = f2bf(x0 > 0.f ? x0 : 0.f);   // ternary: -0.0 -> +0
            hv.y = f2bf(x1 > 0.f ? x1 : 0.f);
            hv.z = f2bf(x2 > 0.f ? x2 : 0.f);
            hv.w = f2bf(x3 > 0.f ? x3 : 0.f);
            *(ushort4*)(Hs + p * 136 + m0) = hv;
        }
    }
    __syncthreads();

    // ---- GEMM2: wave w owns c rows [w*64, w*64+64)
    f32x4 acc2[4][4];
#pragma unroll
    for (int mt = 0; mt < 4; ++mt)
#pragma unroll
        for (int nt = 0; nt < 4; ++nt) {
            f32x4 zz = {0.f, 0.f, 0.f, 0.f};
            acc2[mt][nt] = zz;
        }
#pragma unroll
    for (int k0i = 0; k0i < 4; ++k0i) {
        s16x8 af[4], hf[4];
#pragma unroll
        for (int mt = 0; mt < 4; ++mt)
            af[mt] = *(const s16x8*)(g_W2f + (((w * 4 + k0i) * 4 + mt) << 9) + L * 8);
#pragma unroll
        for (int nt = 0; nt < 4; ++nt)
            hf[nt] = *(const s16x8*)(Hs + (nt * 16 + ln) * 136 + k0i * 32 + quad * 8);
#pragma unroll
        for (int mt = 0; mt < 4; ++mt)
#pragma unroll
            for (int nt = 0; nt < 4; ++nt)
                acc2[mt][nt] = __builtin_amdgcn_mfma_f32_16x16x32_bf16(
                    af[mt], hf[nt], acc2[mt][nt], 0, 0, 0);
    }
    __syncthreads();  // Hs/Xs dead; Ys aliases them

    // epilogue 2: bias+relu, stage Ys[p][c]
#pragma unroll
    for (int mt = 0; mt < 4; ++mt) {
        int c0 = w * 64 + mt * 16 + quad * 4;
        float4 bv = *(const float4*)(b2 + c0);
#pragma unroll
        for (int nt = 0; nt < 4; ++nt) {
            int p = nt * 16 + ln;
            float x0 = acc2[mt][nt][0] + bv.x;
            float x1 = acc2[mt][nt][1] + bv.y;
            float x2 = acc2[mt][nt][2] + bv.z;
            float x3 = acc2[mt][nt][3] + bv.w;
            ushort4 yv;
            yv.x = f2bf(x0 > 0.f ? x0 : 0.f);
            yv.y = f2bf(x1 > 0.f ? x1 : 0.f);
            yv.z = f2bf(x2 > 0.f ? x2 : 0.f);
            yv.w = f2bf(x3 > 0.f ? x3 : 0.f);
            *(ushort4*)(Ys + p * 264 + c0) = yv;
        }
    }
    __syncthreads();

    // coalesced store: g_Yf[b][n0+p][0..255], 512B per point row
    u16* dstY = g_Yf + ((size_t)b * N_ + n0) * COUT;
#pragma unroll
    for (int i = 0; i < 8; ++i) {
        int g = i * 256 + tid;
        int p = g >> 5, c16 = g & 31;
        *(uint4*)(dstY + (size_t)p * COUT + c16 * 8) =
            *(const uint4*)(Ys + p * 264 + c16 * 8);
    }
}

// ---------------------------------------------------------------------------
// Kernel 2: gather neighbors + max over K. Block = 32 queries of one batch
// (R5 used 64: LDS 43 KB -> 3 blocks/CU -> 27.7% occupancy, latency-bound
// with all pipes idle. 32 queries cuts LDS to 22.5 KB -> 7 blocks/CU ->
// ~87% occupancy cap for 3x the latency hiding).
// One wave per query per iteration; lane holds 4 channels (8B) -> each (m,k)
// read is one coalesced 512B row. Max in raw ushort domain: post-ReLU bf16
// (sign bit always 0) is order-isomorphic to uint16 -> exact bf16 max.
// Final store converts bf16 -> fp32 (output buffer is float32).
// ---------------------------------------------------------------------------
__global__ __launch_bounds__(256) void gather_max(
        const int* __restrict__ nbr, float* __restrict__ out) {
    __shared__ __align__(16) int sidx[32 * K_];    // 4 KB
    __shared__ __align__(16) u16 ymax[COUT * 36];  // 18.4 KB, 72 B row stride

    const int tid = threadIdx.x;
    const int b   = blockIdx.y;
    const int m0  = blockIdx.x * 32;

    // stage neighbor indices: 1024 ints, one int4 per thread
    if (m0 + (tid >> 3) < M_)
        *(int4*)(sidx + tid * 4) =
            *(const int4*)(nbr + ((size_t)b * M_ + m0) * K_ + tid * 4);
    __syncthreads();

    const int w = tid >> 6, L = tid & 63;
    const u16* base = g_Yf + (size_t)b * N_ * COUT + L * 4;
#pragma unroll
    for (int i = 0; i < 8; ++i) {
        int ml = w * 8 + i;
        if (m0 + ml >= M_) break;
        ushort4 mx; mx.x = 0; mx.y = 0; mx.z = 0; mx.w = 0;
#pragma unroll
        for (int k = 0; k < K_; ++k) {
            int idx = __builtin_amdgcn_readfirstlane(sidx[ml * K_ + k]);
            idx = ((unsigned)idx < (unsigned)N_) ? idx : 0;   // defensive clamp
            ushort4 v = *(const ushort4*)(base + (size_t)idx * COUT);
            mx.x = v.x > mx.x ? v.x : mx.x;
            mx.y = v.y > mx.y ? v.y : mx.y;
            mx.z = v.z > mx.z ? v.z : mx.z;
            mx.w = v.w > mx.w ? v.w : mx.w;
        }
        u16* yp = ymax + (L * 4) * 36 + ml;
        yp[0] = mx.x; yp[36] = mx.y; yp[72] = mx.z; yp[108] = mx.w;
    }
    __syncthreads();

    // transpose out of LDS, expand bf16 -> fp32:
    // out[b][c][m0..m0+31], one float4 per thread per iter, coalesced
    int valid = M_ - m0; if (valid > 32) valid = 32;   // tail valid = 16 (mult of 4)
#pragma unroll
    for (int i = 0; i < 8; ++i) {
        int c  = i * 32 + (tid >> 3);
        int mc = (tid & 7) << 2;
        if (mc + 4 <= valid) {
            const u16* src = ymax + c * 36 + mc;
            float4 v;
            v.x = bf2f(src[0]); v.y = bf2f(src[1]);
            v.z = bf2f(src[2]); v.w = bf2f(src[3]);
            *(float4*)(out + (size_t)(b * COUT + c) * M_ + m0 + mc) = v;
        }
    }
}

extern "C" void kernel_launch(void* const* d_in, const int* in_sizes, int n_in,
                              void* d_out, int out_size, void* d_ws, size_t ws_size,
                              hipStream_t stream) {
    // inputs (all fp32 except neighbor_idx int32), per the reference:
    // 0=query_xyz(unused) 1=support_xyz 2=features 3=neighbor_idx
    // 4=W1 5=b1 6=W2 7=b2. Output: fp32 [B][C_OUT][M].
    const float* xyz  = (const float*)d_in[1];
    const float* feat = (const float*)d_in[2];
    const int*   nbr  = (const int*)d_in[3];
    const float* W1   = (const float*)d_in[4];
    const float* b1   = (const float*)d_in[5];
    const float* W2   = (const float*)d_in[6];
    const float* b2   = (const float*)d_in[7];
    float* out = (float*)d_out;
    (void)d_ws; (void)ws_size;

    prep_weights<<<176, 256, 0, stream>>>(W1, W2);   // 176*256 = 45056
    conv_fused<<<dim3(N_ / 64, B_), 256, 0, stream>>>(feat, xyz, b1, b2);
    gather_max<<<dim3((M_ + 31) / 32, B_), 256, 0, stream>>>(nbr, out);
}